// Round 8
// baseline (10909.695 us; speedup 1.0000x reference)
//
#include <hip/hip_runtime.h>
#include <hip/hip_bf16.h>
#include <hip/hip_fp16.h>
#include <stdint.h>

#define BB 64
#define TT 512
#define II 256
#define HH 1024
#define G4 4096

typedef unsigned short u16;
typedef unsigned long long u64;
typedef __attribute__((ext_vector_type(8))) _Float16 h8;
typedef __attribute__((ext_vector_type(4))) float f32x4;

__device__ __forceinline__ u16 f2h(float x){
  _Float16 h = (_Float16)x;
  return __builtin_bit_cast(u16, h);
}
__device__ __forceinline__ float sigm(float x){ return 1.0f/(1.0f + __expf(-x)); }
__device__ __forceinline__ float tanh_f(float x){ return 1.0f - 2.0f/(1.0f + __expf(2.0f*x)); }

// agent-scope (cross-XCD coherent) 16B load as two relaxed 8B atomics
__device__ __forceinline__ h8 aload16(const u16* p){
  union { u64 v[2]; h8 h; } u;
  const u64* q = (const u64*)p;
  u.v[0] = __hip_atomic_load(q,     __ATOMIC_RELAXED, __HIP_MEMORY_SCOPE_AGENT);
  u.v[1] = __hip_atomic_load(q + 1, __ATOMIC_RELAXED, __HIP_MEMORY_SCOPE_AGENT);
  return u.h;
}

// ---------------- prep kernels ----------------
__global__ void bias_comb_kernel(const float* __restrict__ a, const float* __restrict__ b,
                                 float* __restrict__ o, int n){
  int i = blockIdx.x*blockDim.x + threadIdx.x;
  if (i < n) o[i] = a[i] + b[i];
}

// x: [B][T][I] fp32 -> xb: [(t*B+b)][I] fp16
__global__ void xconv_kernel(const float* __restrict__ x, u16* __restrict__ xb){
  int m = blockIdx.x;            // t*BB + b
  int t = m >> 6, b = m & 63;
  const float4* src = (const float4*)(x + ((size_t)b*TT + t)*II);
  float4 v = src[threadIdx.x];   // 64 threads * 4 = 256 = II
  ushort4 o; o.x=f2h(v.x); o.y=f2h(v.y); o.z=f2h(v.z); o.w=f2h(v.w);
  ((ushort4*)(xb + (size_t)m*II))[threadIdx.x] = o;
}

// Concat-K weight swizzle into MFMA B-frag order (fp32 -> fp16). 16-j blocks:
// dst s8 = ((jg*KS + ks)*4 + g)*64 + lane ; element:
//   n = g*1024 + jg*16 + (lane&15), k = ks*32 + (lane>>4)*8 + j
// (verified layout from rounds 0-2)
__global__ void wswz_kernel(const float* __restrict__ Wa, int Ka,
                            const float* __restrict__ Wb, int Kb,
                            u16* __restrict__ dst, int KS){
  int s8 = blockIdx.x*blockDim.x + threadIdx.x;
  int lane = s8 & 63;
  int g    = (s8 >> 6) & 3;
  int rest = s8 >> 8;
  int ks   = rest % KS;
  int jg   = rest / KS;
  if (jg >= 64) return;
  int id = lane & 15, quad = lane >> 4;
  int n = g*HH + jg*16 + id;
  int k = ks*32 + quad*8;
  const float* src = (k < Ka) ? (Wa + (size_t)n*Ka + k) : (Wb + (size_t)n*Kb + (k - Ka));
  float4 v0 = ((const float4*)src)[0];
  float4 v1 = ((const float4*)src)[1];
  ushort4 o0; o0.x=f2h(v0.x); o0.y=f2h(v0.y); o0.z=f2h(v0.z); o0.w=f2h(v0.w);
  ushort4 o1; o1.x=f2h(v1.x); o1.y=f2h(v1.y); o1.z=f2h(v1.z); o1.w=f2h(v1.w);
  u16* d = dst + (size_t)s8*8;
  ((ushort4*)d)[0] = o0;
  ((ushort4*)d)[1] = o1;
}

#define MFMA4(Av, WL, MT) \
  a[MT][0] = __builtin_amdgcn_mfma_f32_16x16x32_f16((Av), (WL)[0], a[MT][0], 0,0,0); \
  a[MT][1] = __builtin_amdgcn_mfma_f32_16x16x32_f16((Av), (WL)[1], a[MT][1], 0,0,0); \
  a[MT][2] = __builtin_amdgcn_mfma_f32_16x16x32_f16((Av), (WL)[2], a[MT][2], 0,0,0); \
  a[MT][3] = __builtin_amdgcn_mfma_f32_16x16x32_f16((Av), (WL)[3], a[MT][3], 0,0,0);

// ---------------- fused 2-layer persistent LSTM ----------------
// 128 blocks x 256 threads. blocks 0..63: layer0 (16 h-cols each); 64..127: layer1.
// HALVED h-broadcast: 64 consumer blocks per layer instead of 128 -> fabric h
// traffic 48 -> 24 MB/epoch, and each wave runs 4 B-frags per A-load (2x MFMA
// per load vs round-5). K-split across waves; weights preloaded in VGPRs
// (L1: 16 ksteps x 4 frags = 256 VGPR). Sync protocol = round-5 verbatim
// (block stamps, 8-slot rings, lazy credit, 3/2 barriers per epoch).
__launch_bounds__(256, 1)
__global__ void lstm_fused_kernel(const u16* __restrict__ xb,
                                  const u16* __restrict__ Wsw0,
                                  const u16* __restrict__ Wsw1,
                                  const float* __restrict__ bias0,
                                  const float* __restrict__ bias1,
                                  u16* __restrict__ h0buf,   // 8 slots [64][1024] fp16
                                  u16* __restrict__ h1buf,   // 8 slots
                                  float* __restrict__ hfin,  // [2][64][1024] fp32
                                  int* __restrict__ stamp0,  // 64 slots, stride 32 ints
                                  int* __restrict__ stamp1){ // 64 slots, stride 32 ints
  __shared__ float Gs[4][64][68];    // [wave][gate-row 4g x 16j][batch 64+pad]
  const int blk = blockIdx.x;
  const int layer = blk >> 6;
  const int jg = blk & 63;
  const int tid = threadIdx.x, wave = tid >> 6, lane = tid & 63;
  const int id = lane & 15, quad = lane >> 4;
  const int KS = layer ? 64 : 40;
  const int KSW = layer ? 16 : 10;
  const u16* Wblk = (layer ? Wsw1 : Wsw0) + (size_t)jg * KS * 2048;
  const int cb = tid >> 2, jq = tid & 3;  // cell phase: batch cb, j-quad jq
  const int j0 = jg * 16;
  const float* Bp = layer ? bias1 : bias0;
  float bs[4][4];
  #pragma unroll
  for (int g = 0; g < 4; ++g)
    #pragma unroll
    for (int jj = 0; jj < 4; ++jj)
      bs[g][jj] = Bp[g*HH + j0 + jq*4 + jj];
  float c4[4] = {0.f, 0.f, 0.f, 0.f};
  const int wb = wave * KSW;

  if (layer == 0){
    // ---- preload weight fragment: 10 ksteps x 4 frags = 160 VGPR ----
    h8 w[10][4];
    #pragma unroll
    for (int l = 0; l < 10; ++l){
      const u16* wl = Wblk + (size_t)(wb + l)*2048 + lane*8;
      w[l][0] = *(const h8*)(wl);
      w[l][1] = *(const h8*)(wl +  512);
      w[l][2] = *(const h8*)(wl + 1024);
      w[l][3] = *(const h8*)(wl + 1536);
    }
    // wave w covers k [w*320, w*320+320): wave0 = 256 x-cols + h[0:64); waves1-3 all h
    const int lmin = (wave == 0) ? 8 : 0;      // first l that reads h
    int credit = 0;
    for (int t = 0; t < TT; ++t){
      const u16* hA = h0buf + ((size_t)(t & 7) << 16);        // h0[t-1]
      u16* hout     = h0buf + ((size_t)((t + 1) & 7) << 16);  // h0[t]
      f32x4 a[4][4] = {};
      // ---- x-part (wave0 only): h-independent, overlaps peers' tail ----
      if (wave == 0){
        #pragma unroll
        for (int l = 0; l < 8; ++l){
          #pragma unroll
          for (int mt = 0; mt < 4; ++mt){
            int abm = mt*16 + id;
            h8 A = *(const h8*)(xb + (((size_t)t*64 + abm) << 8) + l*32 + quad*8);
            MFMA4(A, w[l], mt);
          }
        }
      }
      // ---- wait (wave0 lanes): all 64 L0 peers published h0[t-1]; lazy credit ----
      if (tid < 64){
        while (__hip_atomic_load(stamp0 + tid*32, __ATOMIC_RELAXED, __HIP_MEMORY_SCOPE_AGENT) < t)
          __builtin_amdgcn_s_sleep(2);
        // before overwriting slot (t+1)&7 (= y0[t-8]), all L1 >= t-7
        while (credit < t - 7){
          int s = __hip_atomic_load(stamp1 + tid*32, __ATOMIC_RELAXED, __HIP_MEMORY_SCOPE_AGENT);
          #pragma unroll
          for (int off = 32; off; off >>= 1){
            int s2 = __shfl_xor(s, off);
            s = s < s2 ? s : s2;
          }
          credit = s;
          if (credit < t - 7) __builtin_amdgcn_s_sleep(8);
        }
      }
      __syncthreads();
      // ---- h-part ----
      #pragma unroll
      for (int l = 0; l < 10; ++l){
        if (l >= lmin){
          int hcol = (wb + l)*32 - 256 + quad*8;
          #pragma unroll
          for (int mt = 0; mt < 4; ++mt){
            int abm = mt*16 + id;
            h8 A = aload16(hA + ((size_t)abm << 10) + hcol);
            MFMA4(A, w[l], mt);
          }
        }
      }
      // ---- exchange: D lane(id,quad) reg r -> batch mt*16+quad*4+r, row g*16+id ----
      #pragma unroll
      for (int mt = 0; mt < 4; ++mt)
        #pragma unroll
        for (int g = 0; g < 4; ++g)
          *(f32x4*)&Gs[wave][g*16 + id][mt*16 + quad*4] = a[mt][g];
      __syncthreads();
      // ---- cell phase: 4 cells (batch cb, j = j0 + jq*4 + jj) ----
      ushort4 hb; float4 hf;
      #pragma unroll
      for (int jj = 0; jj < 4; ++jj){
        int jl = jq*4 + jj;
        float p[4];
        #pragma unroll
        for (int g = 0; g < 4; ++g)
          p[g] = Gs[0][g*16 + jl][cb] + Gs[1][g*16 + jl][cb]
               + Gs[2][g*16 + jl][cb] + Gs[3][g*16 + jl][cb] + bs[g][jj];
        float iv = sigm(p[0]), fv = sigm(p[1]), gv = tanh_f(p[2]), ov = sigm(p[3]);
        float c = fv*c4[jj] + iv*gv;
        c4[jj] = c;
        float h = ov * tanh_f(c);
        (&hf.x)[jj] = h;
        ((u16*)&hb)[jj] = f2h(h);
      }
      union { ushort4 s; u64 v; } pk; pk.s = hb;
      __hip_atomic_store((u64*)&hout[(size_t)cb*HH + j0 + jq*4],
                         pk.v, __ATOMIC_RELAXED, __HIP_MEMORY_SCOPE_AGENT);
      if (t == TT - 1)
        *(float4*)&hfin[(size_t)cb*HH + j0 + jq*4] = hf;
      __syncthreads();   // drains vmcnt: h-stores ack'd at coherence point
      if (tid == 0)
        __hip_atomic_store(stamp0 + jg*32, t + 1, __ATOMIC_RELAXED, __HIP_MEMORY_SCOPE_AGENT);
    }
  } else {
    // ---- preload weight fragment: 16 ksteps x 4 frags = 256 VGPR ----
    h8 w[16][4];
    #pragma unroll
    for (int l = 0; l < 16; ++l){
      const u16* wl = Wblk + (size_t)(wb + l)*2048 + lane*8;
      w[l][0] = *(const h8*)(wl);
      w[l][1] = *(const h8*)(wl +  512);
      w[l][2] = *(const h8*)(wl + 1024);
      w[l][3] = *(const h8*)(wl + 1536);
    }
    // wave w covers k [w*512, (w+1)*512): waves 0-1 read y0, waves 2-3 read h1
    const int koff = (wave & 1) * 512;
    for (int t = 0; t < TT; ++t){
      const u16* y0  = h0buf + ((size_t)((t + 1) & 7) << 16); // y0[t] = h0[t]
      const u16* hA1 = h1buf + ((size_t)(t & 7) << 16);       // h1[t-1]
      u16* hout      = h1buf + ((size_t)((t + 1) & 7) << 16); // h1[t]
      const u16* hsrc = (wave < 2) ? y0 : hA1;
      // ---- wait: L0 published h0[t] (stamp >= t+1); L1 peers published h1[t-1] ----
      if (tid < 64){
        while (__hip_atomic_load(stamp0 + tid*32, __ATOMIC_RELAXED, __HIP_MEMORY_SCOPE_AGENT) < t + 1)
          __builtin_amdgcn_s_sleep(2);
      } else if (tid < 128){
        while (__hip_atomic_load(stamp1 + (tid - 64)*32, __ATOMIC_RELAXED, __HIP_MEMORY_SCOPE_AGENT) < t)
          __builtin_amdgcn_s_sleep(2);
      }
      __syncthreads();
      f32x4 a[4][4] = {};
      #pragma unroll
      for (int l = 0; l < 16; ++l){
        int col = koff + l*32 + quad*8;
        #pragma unroll
        for (int mt = 0; mt < 4; ++mt){
          int abm = mt*16 + id;
          h8 A = aload16(hsrc + ((size_t)abm << 10) + col);
          MFMA4(A, w[l], mt);
        }
      }
      #pragma unroll
      for (int mt = 0; mt < 4; ++mt)
        #pragma unroll
        for (int g = 0; g < 4; ++g)
          *(f32x4*)&Gs[wave][g*16 + id][mt*16 + quad*4] = a[mt][g];
      __syncthreads();
      ushort4 hb; float4 hf;
      #pragma unroll
      for (int jj = 0; jj < 4; ++jj){
        int jl = jq*4 + jj;
        float p[4];
        #pragma unroll
        for (int g = 0; g < 4; ++g)
          p[g] = Gs[0][g*16 + jl][cb] + Gs[1][g*16 + jl][cb]
               + Gs[2][g*16 + jl][cb] + Gs[3][g*16 + jl][cb] + bs[g][jj];
        float iv = sigm(p[0]), fv = sigm(p[1]), gv = tanh_f(p[2]), ov = sigm(p[3]);
        float c = fv*c4[jj] + iv*gv;
        c4[jj] = c;
        float h = ov * tanh_f(c);
        (&hf.x)[jj] = h;
        ((u16*)&hb)[jj] = f2h(h);
      }
      union { ushort4 s; u64 v; } pk; pk.s = hb;
      __hip_atomic_store((u64*)&hout[(size_t)cb*HH + j0 + jq*4],
                         pk.v, __ATOMIC_RELAXED, __HIP_MEMORY_SCOPE_AGENT);
      if (t == TT - 1)
        *(float4*)&hfin[(size_t)(BB*HH) + (size_t)cb*HH + j0 + jq*4] = hf;
      __syncthreads();   // drains vmcnt: h-stores ack'd at coherence point
      if (tid == 0)
        __hip_atomic_store(stamp1 + jg*32, t + 1, __ATOMIC_RELAXED, __HIP_MEMORY_SCOPE_AGENT);
    }
  }
}

// ---------------- FC head ----------------
__global__ void fc_kernel(const float* __restrict__ hfin, const float* __restrict__ fcw,
                          const float* __restrict__ fcb, float* __restrict__ out){
  int row = blockIdx.x;          // 0..127  (0..63 layer0 hT, 64..127 layer1 hT)
  int lane = threadIdx.x;        // 64
  const float* h = hfin + (size_t)row*HH;
  float a0 = 0.f, a1 = 0.f;
  for (int j = lane; j < HH; j += 64){
    float v = h[j]; v = v > 0.f ? v : 0.f;
    a0 += v * fcw[j];
    a1 += v * fcw[HH + j];
  }
  for (int off = 32; off; off >>= 1){ a0 += __shfl_down(a0, off); a1 += __shfl_down(a1, off); }
  if (lane == 0){
    out[row*2 + 0] = 1.f/(1.f + __expf(-(a0 + fcb[0])));
    out[row*2 + 1] = 1.f/(1.f + __expf(-(a1 + fcb[1])));
  }
}

// ---------------- launch ----------------
extern "C" void kernel_launch(void* const* d_in, const int* in_sizes, int n_in,
                              void* d_out, int out_size, void* d_ws, size_t ws_size,
                              hipStream_t stream){
  (void)in_sizes; (void)n_in; (void)out_size; (void)ws_size;
  const float* x    = (const float*)d_in[0];
  const float* Wih0 = (const float*)d_in[1];
  const float* Whh0 = (const float*)d_in[2];
  const float* bih0 = (const float*)d_in[3];
  const float* bhh0 = (const float*)d_in[4];
  const float* Wih1 = (const float*)d_in[5];
  const float* Whh1 = (const float*)d_in[6];
  const float* bih1 = (const float*)d_in[7];
  const float* bhh1 = (const float*)d_in[8];
  const float* fcw  = (const float*)d_in[9];
  const float* fcb  = (const float*)d_in[10];

  char* w = (char*)d_ws;
  size_t off = 0;
  auto take = [&](size_t bytes)->char*{
    char* p = w + off; off += (bytes + 255) & ~(size_t)255; return p;
  };
  u16*   xb    = (u16*)  take((size_t)TT*BB*II*2);       // 16 MB
  u16*   wsw0  = (u16*)  take((size_t)G4*1280*2);        // 10 MB  (K=256+1024)
  u16*   wsw1  = (u16*)  take((size_t)G4*2048*2);        // 16 MB  (K=1024+1024)
  float* bias0 = (float*)take(G4*4);
  float* bias1 = (float*)take(G4*4);
  u16*   h0buf = (u16*)  take(8*(size_t)BB*HH*2);        // 1 MB ring (8 slots)
  u16*   h1buf = (u16*)  take(8*(size_t)BB*HH*2);
  float* hfin  = (float*)take(2*(size_t)BB*HH*4);        // 512 KB
  int*   stamp0= (int*)  take(64*128);                   // 64 slots x 128B
  int*   stamp1= (int*)  take(64*128);

  hipMemsetAsync(h0buf, 0, 8*(size_t)BB*HH*2, stream);
  hipMemsetAsync(h1buf, 0, 8*(size_t)BB*HH*2, stream);
  hipMemsetAsync(stamp0, 0, 64*128, stream);
  hipMemsetAsync(stamp1, 0, 64*128, stream);

  bias_comb_kernel<<<16, 256, 0, stream>>>(bih0, bhh0, bias0, G4);
  bias_comb_kernel<<<16, 256, 0, stream>>>(bih1, bhh1, bias1, G4);
  xconv_kernel<<<TT*BB, 64, 0, stream>>>(x, xb);
  // L0: 64*40*4*64/256 = 2560 blocks; L1: 64*64*4*64/256 = 4096 blocks
  wswz_kernel<<<2560, 256, 0, stream>>>(Wih0, II, Whh0, HH, wsw0, 40);
  wswz_kernel<<<4096, 256, 0, stream>>>(Wih1, HH, Whh1, HH, wsw1, 64);

  lstm_fused_kernel<<<128, 256, 0, stream>>>(xb, wsw0, wsw1, bias0, bias1,
                                             h0buf, h1buf, hfin, stamp0, stamp1);
  fc_kernel<<<2*BB, 64, 0, stream>>>(hfin, fcw, fcb, (float*)d_out);
}

// Round 9
// 8362.263 us; speedup vs baseline: 1.3046x; 1.3046x over previous
//
#include <hip/hip_runtime.h>
#include <hip/hip_bf16.h>
#include <hip/hip_fp16.h>
#include <stdint.h>

#define BB 64
#define TT 512
#define II 256
#define HH 1024
#define G4 4096

typedef unsigned short u16;
typedef unsigned long long u64;
typedef __attribute__((ext_vector_type(8))) _Float16 h8;
typedef __attribute__((ext_vector_type(4))) float f32x4;

__device__ __forceinline__ u16 f2h(float x){
  _Float16 h = (_Float16)x;
  return __builtin_bit_cast(u16, h);
}
__device__ __forceinline__ float sigm(float x){ return 1.0f/(1.0f + __expf(-x)); }
__device__ __forceinline__ float tanh_f(float x){ return 1.0f - 2.0f/(1.0f + __expf(2.0f*x)); }

// agent-scope (cross-XCD coherent) 16B load as two relaxed 8B atomics
__device__ __forceinline__ h8 aload16(const u16* p){
  union { u64 v[2]; h8 h; } u;
  const u64* q = (const u64*)p;
  u.v[0] = __hip_atomic_load(q,     __ATOMIC_RELAXED, __HIP_MEMORY_SCOPE_AGENT);
  u.v[1] = __hip_atomic_load(q + 1, __ATOMIC_RELAXED, __HIP_MEMORY_SCOPE_AGENT);
  return u.h;
}

// ---------------- prep kernels ----------------
__global__ void bias_comb_kernel(const float* __restrict__ a, const float* __restrict__ b,
                                 float* __restrict__ o, int n){
  int i = blockIdx.x*blockDim.x + threadIdx.x;
  if (i < n) o[i] = a[i] + b[i];
}

// x: [B][T][I] fp32 -> xb: [(t*B+b)][I] fp16
__global__ void xconv_kernel(const float* __restrict__ x, u16* __restrict__ xb){
  int m = blockIdx.x;            // t*BB + b
  int t = m >> 6, b = m & 63;
  const float4* src = (const float4*)(x + ((size_t)b*TT + t)*II);
  float4 v = src[threadIdx.x];   // 64 threads * 4 = 256 = II
  ushort4 o; o.x=f2h(v.x); o.y=f2h(v.y); o.z=f2h(v.z); o.w=f2h(v.w);
  ((ushort4*)(xb + (size_t)m*II))[threadIdx.x] = o;
}

// Concat-K weight swizzle into MFMA B-frag order (fp32 -> fp16).
// 8-j blocks: frag f in {0,1}; within frag, id in [0,16):
//   gate g = f*2 + (id>>3), j = jg8*8 + (id&7), n = g*HH + j
//   k = ks*32 + quad*8 + elem
// dst s8 = ((jg8*KS + ks)*2 + f)*64 + lane, 8 u16 each.
__global__ void wswz_kernel(const float* __restrict__ Wa, int Ka,
                            const float* __restrict__ Wb, int Kb,
                            u16* __restrict__ dst, int KS){
  int s8 = blockIdx.x*blockDim.x + threadIdx.x;
  int lane = s8 & 63;
  int f    = (s8 >> 6) & 1;
  int rest = s8 >> 7;
  int ks   = rest % KS;
  int jg8  = rest / KS;
  if (jg8 >= 128) return;
  int id = lane & 15, quad = lane >> 4;
  int g = f*2 + (id >> 3);
  int n = g*HH + jg8*8 + (id & 7);
  int k = ks*32 + quad*8;
  const float* src = (k < Ka) ? (Wa + (size_t)n*Ka + k) : (Wb + (size_t)n*Kb + (k - Ka));
  float4 v0 = ((const float4*)src)[0];
  float4 v1 = ((const float4*)src)[1];
  ushort4 o0; o0.x=f2h(v0.x); o0.y=f2h(v0.y); o0.z=f2h(v0.z); o0.w=f2h(v0.w);
  ushort4 o1; o1.x=f2h(v1.x); o1.y=f2h(v1.y); o1.z=f2h(v1.z); o1.w=f2h(v1.w);
  u16* d = dst + (size_t)s8*8;
  ((ushort4*)d)[0] = o0;
  ((ushort4*)d)[1] = o1;
}

// ---------------- fused 2-layer persistent LSTM, bulk-staged loads ----------------
// ROUND-5 BASE (8.49 ms, best): 256 blocks x 256 threads; blocks 0..127 layer0,
// 128..255 layer1; j=8 per block; K-split across waves; weights in VGPRs;
// block stamps + 8-slot rings + lazy credit. Sync protocol byte-identical.
// NEW: bulk load staging. All h loads of a phase (32 aload16 = 64 8B agent
// loads = 128 VGPR) are issued BEFORE any consuming MFMA, maximizing
// memory-level parallelism (round-5's 136-VGPR build could keep only ~10 loads
// in flight inside its load->mfma->load chain). L1 = 2 phases; L0 h = 1 phase.
// L0 x-ksteps rebalanced 2/wave (pre-wait), h-ksteps 8/wave.
__launch_bounds__(256, 1)
__global__ void lstm_fused_kernel(const u16* __restrict__ xb,
                                  const u16* __restrict__ Wsw0,
                                  const u16* __restrict__ Wsw1,
                                  const float* __restrict__ bias0,
                                  const float* __restrict__ bias1,
                                  u16* __restrict__ h0buf,   // 8 slots [64][1024] fp16
                                  u16* __restrict__ h1buf,   // 8 slots
                                  float* __restrict__ hfin,  // [2][64][1024] fp32
                                  int* __restrict__ stamp0,  // 128 slots, stride 32 ints
                                  int* __restrict__ stamp1){ // 128 slots, stride 32 ints
  __shared__ float Gs[4][32][68];    // [wave][gate-row 2f x 16id][batch 64+pad]
  const int blk = blockIdx.x;
  const int layer = blk >> 7;
  const int jg = blk & 127;
  const int tid = threadIdx.x, wave = tid >> 6, lane = tid & 63;
  const int id = lane & 15, quad = lane >> 4;
  const int KS = layer ? 64 : 40;
  const u16* Wblk = (layer ? Wsw1 : Wsw0) + (size_t)jg * KS * 1024;
  const int cb = tid >> 2, jq = tid & 3;  // cell phase: batch cb, j-pair jq
  const int j0 = jg * 8;
  const float* Bp = layer ? bias1 : bias0;
  float bs[4][2];
  #pragma unroll
  for (int g = 0; g < 4; ++g)
    #pragma unroll
    for (int jj = 0; jj < 2; ++jj)
      bs[g][jj] = Bp[g*HH + j0 + jq*2 + jj];
  float c2[2] = {0.f, 0.f};

  if (layer == 0){
    // ---- weights: wave w owns x-ksteps {2w,2w+1} + h-ksteps {8+8w..8+8w+7} ----
    h8 w0[10], w1[10];
    #pragma unroll
    for (int i = 0; i < 10; ++i){
      int ks = (i < 2) ? (2*wave + i) : (8 + 8*wave + (i - 2));
      const u16* wl = Wblk + (size_t)ks*1024 + lane*8;
      w0[i] = *(const h8*)(wl);
      w1[i] = *(const h8*)(wl + 512);
    }
    int credit = 0;
    for (int t = 0; t < TT; ++t){
      const u16* hA = h0buf + ((size_t)(t & 7) << 16);        // h0[t-1]
      u16* hout     = h0buf + ((size_t)((t + 1) & 7) << 16);  // h0[t]
      f32x4 a0[4] = {}, a1[4] = {};
      // ---- x-part: h-independent, overlaps the stamp wait below ----
      #pragma unroll
      for (int i = 0; i < 2; ++i){
        int xcol = (2*wave + i)*32 + quad*8;
        #pragma unroll
        for (int mt = 0; mt < 4; ++mt){
          h8 A = *(const h8*)(xb + (((size_t)t*64 + mt*16 + id) << 8) + xcol);
          a0[mt] = __builtin_amdgcn_mfma_f32_16x16x32_f16(A, w0[i], a0[mt], 0,0,0);
          a1[mt] = __builtin_amdgcn_mfma_f32_16x16x32_f16(A, w1[i], a1[mt], 0,0,0);
        }
      }
      // ---- wait: all L0 peers published h0[t-1]; lazy anti-overwrite credit ----
      if (tid < 128){
        while (__hip_atomic_load(stamp0 + tid*32, __ATOMIC_RELAXED, __HIP_MEMORY_SCOPE_AGENT) < t)
          __builtin_amdgcn_s_sleep(2);
      }
      if (tid < 64){
        while (credit < t - 7){
          int sa = __hip_atomic_load(stamp1 + tid*32,      __ATOMIC_RELAXED, __HIP_MEMORY_SCOPE_AGENT);
          int sb = __hip_atomic_load(stamp1 + (64+tid)*32, __ATOMIC_RELAXED, __HIP_MEMORY_SCOPE_AGENT);
          int s = sa < sb ? sa : sb;
          #pragma unroll
          for (int off = 32; off; off >>= 1){
            int s2 = __shfl_xor(s, off);
            s = s < s2 ? s : s2;
          }
          credit = s;
          if (credit < t - 7) __builtin_amdgcn_s_sleep(8);
        }
      }
      __syncthreads();
      // ---- h-part: bulk-stage ALL 32 loads (cols [wave*256, wave*256+256)) ----
      {
        h8 st[32];
        #pragma unroll
        for (int i = 0; i < 8; ++i){
          int hcol = wave*256 + i*32 + quad*8;
          #pragma unroll
          for (int mt = 0; mt < 4; ++mt)
            st[i*4 + mt] = aload16(hA + ((size_t)(mt*16 + id) << 10) + hcol);
        }
        #pragma unroll
        for (int i = 0; i < 8; ++i)
          #pragma unroll
          for (int mt = 0; mt < 4; ++mt){
            a0[mt] = __builtin_amdgcn_mfma_f32_16x16x32_f16(st[i*4+mt], w0[2+i], a0[mt], 0,0,0);
            a1[mt] = __builtin_amdgcn_mfma_f32_16x16x32_f16(st[i*4+mt], w1[2+i], a1[mt], 0,0,0);
          }
      }
      // ---- exchange: D lane(id,quad) reg r -> batch mt*16+quad*4+r, row f*16+id ----
      #pragma unroll
      for (int mt = 0; mt < 4; ++mt){
        *(f32x4*)&Gs[wave][id][mt*16 + quad*4]      = a0[mt];
        *(f32x4*)&Gs[wave][16 + id][mt*16 + quad*4] = a1[mt];
      }
      __syncthreads();
      // ---- cell phase: 2 cells (batch cb, j = j0 + jq*2 + jj) ----
      ushort2 hb; float2 hf;
      #pragma unroll
      for (int jj = 0; jj < 2; ++jj){
        int jl = jq*2 + jj;
        float p[4];
        #pragma unroll
        for (int g = 0; g < 4; ++g){
          int e = (g >> 1)*16 + (g & 1)*8 + jl;
          p[g] = Gs[0][e][cb] + Gs[1][e][cb] + Gs[2][e][cb] + Gs[3][e][cb] + bs[g][jj];
        }
        float iv = sigm(p[0]), fv = sigm(p[1]), gv = tanh_f(p[2]), ov = sigm(p[3]);
        float c = fv*c2[jj] + iv*gv;
        c2[jj] = c;
        float h = ov * tanh_f(c);
        (&hf.x)[jj] = h;
        ((u16*)&hb)[jj] = f2h(h);
      }
      union { ushort2 s; unsigned int v; } pk; pk.s = hb;
      __hip_atomic_store((unsigned int*)&hout[(size_t)cb*HH + j0 + jq*2],
                         pk.v, __ATOMIC_RELAXED, __HIP_MEMORY_SCOPE_AGENT);
      if (t == TT - 1)
        *(float2*)&hfin[(size_t)cb*HH + j0 + jq*2] = hf;
      __syncthreads();   // drains vmcnt: h-stores ack'd at coherence point
      if (tid == 0)
        __hip_atomic_store(stamp0 + jg*32, t + 1, __ATOMIC_RELAXED, __HIP_MEMORY_SCOPE_AGENT);
    }
  } else {
    // ---- preload weight fragment: 16 steps x 2 frags = 128 VGPR ----
    h8 w0[16], w1[16];
    const int wb = wave * 16;
    #pragma unroll
    for (int l = 0; l < 16; ++l){
      const u16* wl = Wblk + (size_t)(wb + l)*1024 + lane*8;
      w0[l] = *(const h8*)(wl);
      w1[l] = *(const h8*)(wl + 512);
    }
    // wave w covers k [w*512, (w+1)*512): waves 0-1 read y0, waves 2-3 read h1
    const int koff = (wave & 1) * 512;
    for (int t = 0; t < TT; ++t){
      const u16* y0  = h0buf + ((size_t)((t + 1) & 7) << 16); // y0[t] = h0[t]
      const u16* hA1 = h1buf + ((size_t)(t & 7) << 16);       // h1[t-1]
      u16* hout      = h1buf + ((size_t)((t + 1) & 7) << 16); // h1[t]
      const u16* hsrc = (wave < 2) ? y0 : hA1;
      // ---- wait: L0 published h0[t] (stamp >= t+1); L1 peers published h1[t-1] ----
      if (tid < 128){
        while (__hip_atomic_load(stamp0 + tid*32, __ATOMIC_RELAXED, __HIP_MEMORY_SCOPE_AGENT) < t + 1)
          __builtin_amdgcn_s_sleep(2);
      } else {
        while (__hip_atomic_load(stamp1 + (tid & 127)*32, __ATOMIC_RELAXED, __HIP_MEMORY_SCOPE_AGENT) < t)
          __builtin_amdgcn_s_sleep(2);
      }
      __syncthreads();
      f32x4 a0[4] = {}, a1[4] = {};
      // ---- phase A: bulk-stage 32 loads (ksteps 0-7), then 64 MFMA ----
      {
        h8 st[32];
        #pragma unroll
        for (int l = 0; l < 8; ++l){
          int col = koff + l*32 + quad*8;
          #pragma unroll
          for (int mt = 0; mt < 4; ++mt)
            st[l*4 + mt] = aload16(hsrc + ((size_t)(mt*16 + id) << 10) + col);
        }
        #pragma unroll
        for (int l = 0; l < 8; ++l)
          #pragma unroll
          for (int mt = 0; mt < 4; ++mt){
            a0[mt] = __builtin_amdgcn_mfma_f32_16x16x32_f16(st[l*4+mt], w0[l], a0[mt], 0,0,0);
            a1[mt] = __builtin_amdgcn_mfma_f32_16x16x32_f16(st[l*4+mt], w1[l], a1[mt], 0,0,0);
          }
      }
      // ---- phase B: bulk-stage 32 loads (ksteps 8-15), then 64 MFMA ----
      {
        h8 st[32];
        #pragma unroll
        for (int l = 0; l < 8; ++l){
          int col = koff + (8 + l)*32 + quad*8;
          #pragma unroll
          for (int mt = 0; mt < 4; ++mt)
            st[l*4 + mt] = aload16(hsrc + ((size_t)(mt*16 + id) << 10) + col);
        }
        #pragma unroll
        for (int l = 0; l < 8; ++l)
          #pragma unroll
          for (int mt = 0; mt < 4; ++mt){
            a0[mt] = __builtin_amdgcn_mfma_f32_16x16x32_f16(st[l*4+mt], w0[8+l], a0[mt], 0,0,0);
            a1[mt] = __builtin_amdgcn_mfma_f32_16x16x32_f16(st[l*4+mt], w1[8+l], a1[mt], 0,0,0);
          }
      }
      #pragma unroll
      for (int mt = 0; mt < 4; ++mt){
        *(f32x4*)&Gs[wave][id][mt*16 + quad*4]      = a0[mt];
        *(f32x4*)&Gs[wave][16 + id][mt*16 + quad*4] = a1[mt];
      }
      __syncthreads();
      ushort2 hb; float2 hf;
      #pragma unroll
      for (int jj = 0; jj < 2; ++jj){
        int jl = jq*2 + jj;
        float p[4];
        #pragma unroll
        for (int g = 0; g < 4; ++g){
          int e = (g >> 1)*16 + (g & 1)*8 + jl;
          p[g] = Gs[0][e][cb] + Gs[1][e][cb] + Gs[2][e][cb] + Gs[3][e][cb] + bs[g][jj];
        }
        float iv = sigm(p[0]), fv = sigm(p[1]), gv = tanh_f(p[2]), ov = sigm(p[3]);
        float c = fv*c2[jj] + iv*gv;
        c2[jj] = c;
        float h = ov * tanh_f(c);
        (&hf.x)[jj] = h;
        ((u16*)&hb)[jj] = f2h(h);
      }
      union { ushort2 s; unsigned int v; } pk; pk.s = hb;
      __hip_atomic_store((unsigned int*)&hout[(size_t)cb*HH + j0 + jq*2],
                         pk.v, __ATOMIC_RELAXED, __HIP_MEMORY_SCOPE_AGENT);
      if (t == TT - 1)
        *(float2*)&hfin[(size_t)(BB*HH) + (size_t)cb*HH + j0 + jq*2] = hf;
      __syncthreads();   // drains vmcnt: h-stores ack'd at coherence point
      if (tid == 0)
        __hip_atomic_store(stamp1 + jg*32, t + 1, __ATOMIC_RELAXED, __HIP_MEMORY_SCOPE_AGENT);
    }
  }
}

// ---------------- FC head ----------------
__global__ void fc_kernel(const float* __restrict__ hfin, const float* __restrict__ fcw,
                          const float* __restrict__ fcb, float* __restrict__ out){
  int row = blockIdx.x;          // 0..127  (0..63 layer0 hT, 64..127 layer1 hT)
  int lane = threadIdx.x;        // 64
  const float* h = hfin + (size_t)row*HH;
  float a0 = 0.f, a1 = 0.f;
  for (int j = lane; j < HH; j += 64){
    float v = h[j]; v = v > 0.f ? v : 0.f;
    a0 += v * fcw[j];
    a1 += v * fcw[HH + j];
  }
  for (int off = 32; off; off >>= 1){ a0 += __shfl_down(a0, off); a1 += __shfl_down(a1, off); }
  if (lane == 0){
    out[row*2 + 0] = 1.f/(1.f + __expf(-(a0 + fcb[0])));
    out[row*2 + 1] = 1.f/(1.f + __expf(-(a1 + fcb[1])));
  }
}

// ---------------- launch ----------------
extern "C" void kernel_launch(void* const* d_in, const int* in_sizes, int n_in,
                              void* d_out, int out_size, void* d_ws, size_t ws_size,
                              hipStream_t stream){
  (void)in_sizes; (void)n_in; (void)out_size; (void)ws_size;
  const float* x    = (const float*)d_in[0];
  const float* Wih0 = (const float*)d_in[1];
  const float* Whh0 = (const float*)d_in[2];
  const float* bih0 = (const float*)d_in[3];
  const float* bhh0 = (const float*)d_in[4];
  const float* Wih1 = (const float*)d_in[5];
  const float* Whh1 = (const float*)d_in[6];
  const float* bih1 = (const float*)d_in[7];
  const float* bhh1 = (const float*)d_in[8];
  const float* fcw  = (const float*)d_in[9];
  const float* fcb  = (const float*)d_in[10];

  char* w = (char*)d_ws;
  size_t off = 0;
  auto take = [&](size_t bytes)->char*{
    char* p = w + off; off += (bytes + 255) & ~(size_t)255; return p;
  };
  u16*   xb    = (u16*)  take((size_t)TT*BB*II*2);       // 16 MB
  u16*   wsw0  = (u16*)  take((size_t)G4*1280*2);        // 10 MB  (K=256+1024)
  u16*   wsw1  = (u16*)  take((size_t)G4*2048*2);        // 16 MB  (K=1024+1024)
  float* bias0 = (float*)take(G4*4);
  float* bias1 = (float*)take(G4*4);
  u16*   h0buf = (u16*)  take(8*(size_t)BB*HH*2);        // 1 MB ring (8 slots)
  u16*   h1buf = (u16*)  take(8*(size_t)BB*HH*2);
  float* hfin  = (float*)take(2*(size_t)BB*HH*4);        // 512 KB
  int*   stamp0= (int*)  take(128*128);                  // 128 slots x 128B
  int*   stamp1= (int*)  take(128*128);

  hipMemsetAsync(h0buf, 0, 8*(size_t)BB*HH*2, stream);
  hipMemsetAsync(h1buf, 0, 8*(size_t)BB*HH*2, stream);
  hipMemsetAsync(stamp0, 0, 128*128, stream);
  hipMemsetAsync(stamp1, 0, 128*128, stream);

  bias_comb_kernel<<<16, 256, 0, stream>>>(bih0, bhh0, bias0, G4);
  bias_comb_kernel<<<16, 256, 0, stream>>>(bih1, bhh1, bias1, G4);
  xconv_kernel<<<TT*BB, 64, 0, stream>>>(x, xb);
  // L0: 128*40*2*64/256 = 2560 blocks; L1: 128*64*2*64/256 = 4096 blocks
  wswz_kernel<<<2560, 256, 0, stream>>>(Wih0, II, Whh0, HH, wsw0, 40);
  wswz_kernel<<<4096, 256, 0, stream>>>(Wih1, HH, Whh1, HH, wsw1, 64);

  lstm_fused_kernel<<<256, 256, 0, stream>>>(xb, wsw0, wsw1, bias0, bias1,
                                             h0buf, h1buf, hfin, stamp0, stamp1);
  fc_kernel<<<2*BB, 64, 0, stream>>>(hfin, fcw, fcb, (float*)d_out);
}

// Round 10
// 5104.734 us; speedup vs baseline: 2.1372x; 1.6381x over previous
//
#include <hip/hip_runtime.h>
#include <hip/hip_bf16.h>
#include <hip/hip_fp16.h>
#include <stdint.h>

#define BB 64
#define TT 512
#define II 256
#define HH 1024
#define G4 4096

typedef unsigned short u16;
typedef unsigned long long u64;
typedef __attribute__((ext_vector_type(8))) _Float16 h8;
typedef __attribute__((ext_vector_type(4))) float f32x4;

__device__ __forceinline__ u16 f2h(float x){
  _Float16 h = (_Float16)x;
  return __builtin_bit_cast(u16, h);
}
__device__ __forceinline__ float sigm(float x){ return 1.0f/(1.0f + __expf(-x)); }
__device__ __forceinline__ float tanh_f(float x){ return 1.0f - 2.0f/(1.0f + __expf(2.0f*x)); }

// agent-scope (cross-XCD coherent) 16B load as two relaxed 8B atomics
__device__ __forceinline__ h8 aload16(const u16* p){
  union { u64 v[2]; h8 h; } u;
  const u64* q = (const u64*)p;
  u.v[0] = __hip_atomic_load(q,     __ATOMIC_RELAXED, __HIP_MEMORY_SCOPE_AGENT);
  u.v[1] = __hip_atomic_load(q + 1, __ATOMIC_RELAXED, __HIP_MEMORY_SCOPE_AGENT);
  return u.h;
}

// coherent read-through 16B load, ISSUE ONLY (no wait): inline asm so the
// compiler can neither sink it into the consume loop nor shrink the in-flight
// window. sc0 sc1 = gfx950 coherent read (bypasses stale L1/L2; same bits the
// agent-scope atomic emits). Atomicity not required: freshness is guaranteed
// by the stamp handshake; we only need read-through semantics.
__device__ __forceinline__ void cld16(h8& dst, const u16* p){
  asm volatile("global_load_dwordx4 %0, %1, off sc0 sc1" : "=v"(dst) : "v"(p));
}
// drain all outstanding loads, then fence the scheduler so MFMAs cannot be
// hoisted above the waitcnt (guide rule: hipcc moves register-only MFMA past
// inline-asm s_waitcnt; sched_barrier(0) is the fix).
__device__ __forceinline__ void vm_drain(){
  asm volatile("s_waitcnt vmcnt(0)" ::: "memory");
  __builtin_amdgcn_sched_barrier(0);
}

// ---------------- prep kernels ----------------
__global__ void bias_comb_kernel(const float* __restrict__ a, const float* __restrict__ b,
                                 float* __restrict__ o, int n){
  int i = blockIdx.x*blockDim.x + threadIdx.x;
  if (i < n) o[i] = a[i] + b[i];
}

// x: [B][T][I] fp32 -> xb: [(t*B+b)][I] fp16
__global__ void xconv_kernel(const float* __restrict__ x, u16* __restrict__ xb){
  int m = blockIdx.x;            // t*BB + b
  int t = m >> 6, b = m & 63;
  const float4* src = (const float4*)(x + ((size_t)b*TT + t)*II);
  float4 v = src[threadIdx.x];   // 64 threads * 4 = 256 = II
  ushort4 o; o.x=f2h(v.x); o.y=f2h(v.y); o.z=f2h(v.z); o.w=f2h(v.w);
  ((ushort4*)(xb + (size_t)m*II))[threadIdx.x] = o;
}

// Concat-K weight swizzle into MFMA B-frag order (fp32 -> fp16).
// 8-j blocks: frag f in {0,1}; within frag, id in [0,16):
//   gate g = f*2 + (id>>3), j = jg8*8 + (id&7), n = g*HH + j
//   k = ks*32 + quad*8 + elem
// dst s8 = ((jg8*KS + ks)*2 + f)*64 + lane, 8 u16 each.
__global__ void wswz_kernel(const float* __restrict__ Wa, int Ka,
                            const float* __restrict__ Wb, int Kb,
                            u16* __restrict__ dst, int KS){
  int s8 = blockIdx.x*blockDim.x + threadIdx.x;
  int lane = s8 & 63;
  int f    = (s8 >> 6) & 1;
  int rest = s8 >> 7;
  int ks   = rest % KS;
  int jg8  = rest / KS;
  if (jg8 >= 128) return;
  int id = lane & 15, quad = lane >> 4;
  int g = f*2 + (id >> 3);
  int n = g*HH + jg8*8 + (id & 7);
  int k = ks*32 + quad*8;
  const float* src = (k < Ka) ? (Wa + (size_t)n*Ka + k) : (Wb + (size_t)n*Kb + (k - Ka));
  float4 v0 = ((const float4*)src)[0];
  float4 v1 = ((const float4*)src)[1];
  ushort4 o0; o0.x=f2h(v0.x); o0.y=f2h(v0.y); o0.z=f2h(v0.z); o0.w=f2h(v0.w);
  ushort4 o1; o1.x=f2h(v1.x); o1.y=f2h(v1.y); o1.z=f2h(v1.z); o1.w=f2h(v1.w);
  u16* d = dst + (size_t)s8*8;
  ((ushort4*)d)[0] = o0;
  ((ushort4*)d)[1] = o1;
}

// ---------------- fused 2-layer persistent LSTM, FORCED bulk-staged loads ----------------
// ROUND-9 BASE (8.36 ms, best). 256 blocks x 256 threads; blocks 0..127 layer0,
// 128..255 layer1; j=8 per block; K-split across waves; weights in VGPRs;
// block stamps + 8-slot rings + lazy credit. Sync protocol byte-identical.
// NEW vs round 9: the staged h loads are inline-asm global_load_dwordx4 sc0 sc1
// (issue-only), so all 32 loads of a phase are IN FLIGHT simultaneously
// (round 9's VGPR=144 proved the compiler had sunk them to a ~4-wide window).
// One s_waitcnt vmcnt(0) + sched_barrier(0) per phase, then the MFMA cluster.
__launch_bounds__(256, 1)
__global__ void lstm_fused_kernel(const u16* __restrict__ xb,
                                  const u16* __restrict__ Wsw0,
                                  const u16* __restrict__ Wsw1,
                                  const float* __restrict__ bias0,
                                  const float* __restrict__ bias1,
                                  u16* __restrict__ h0buf,   // 8 slots [64][1024] fp16
                                  u16* __restrict__ h1buf,   // 8 slots
                                  float* __restrict__ hfin,  // [2][64][1024] fp32
                                  int* __restrict__ stamp0,  // 128 slots, stride 32 ints
                                  int* __restrict__ stamp1){ // 128 slots, stride 32 ints
  __shared__ float Gs[4][32][68];    // [wave][gate-row 2f x 16id][batch 64+pad]
  const int blk = blockIdx.x;
  const int layer = blk >> 7;
  const int jg = blk & 127;
  const int tid = threadIdx.x, wave = tid >> 6, lane = tid & 63;
  const int id = lane & 15, quad = lane >> 4;
  const int KS = layer ? 64 : 40;
  const u16* Wblk = (layer ? Wsw1 : Wsw0) + (size_t)jg * KS * 1024;
  const int cb = tid >> 2, jq = tid & 3;  // cell phase: batch cb, j-pair jq
  const int j0 = jg * 8;
  const float* Bp = layer ? bias1 : bias0;
  float bs[4][2];
  #pragma unroll
  for (int g = 0; g < 4; ++g)
    #pragma unroll
    for (int jj = 0; jj < 2; ++jj)
      bs[g][jj] = Bp[g*HH + j0 + jq*2 + jj];
  float c2[2] = {0.f, 0.f};

  if (layer == 0){
    // ---- weights: wave w owns x-ksteps {2w,2w+1} + h-ksteps {8+8w..8+8w+7} ----
    h8 w0[10], w1[10];
    #pragma unroll
    for (int i = 0; i < 10; ++i){
      int ks = (i < 2) ? (2*wave + i) : (8 + 8*wave + (i - 2));
      const u16* wl = Wblk + (size_t)ks*1024 + lane*8;
      w0[i] = *(const h8*)(wl);
      w1[i] = *(const h8*)(wl + 512);
    }
    int credit = 0;
    for (int t = 0; t < TT; ++t){
      const u16* hA = h0buf + ((size_t)(t & 7) << 16);        // h0[t-1]
      u16* hout     = h0buf + ((size_t)((t + 1) & 7) << 16);  // h0[t]
      f32x4 a0[4] = {}, a1[4] = {};
      // ---- x-part: h-independent, overlaps the stamp wait below ----
      #pragma unroll
      for (int i = 0; i < 2; ++i){
        int xcol = (2*wave + i)*32 + quad*8;
        #pragma unroll
        for (int mt = 0; mt < 4; ++mt){
          h8 A = *(const h8*)(xb + (((size_t)t*64 + mt*16 + id) << 8) + xcol);
          a0[mt] = __builtin_amdgcn_mfma_f32_16x16x32_f16(A, w0[i], a0[mt], 0,0,0);
          a1[mt] = __builtin_amdgcn_mfma_f32_16x16x32_f16(A, w1[i], a1[mt], 0,0,0);
        }
      }
      // ---- wait: all L0 peers published h0[t-1]; lazy anti-overwrite credit ----
      if (tid < 128){
        while (__hip_atomic_load(stamp0 + tid*32, __ATOMIC_RELAXED, __HIP_MEMORY_SCOPE_AGENT) < t)
          __builtin_amdgcn_s_sleep(2);
      }
      if (tid < 64){
        while (credit < t - 7){
          int sa = __hip_atomic_load(stamp1 + tid*32,      __ATOMIC_RELAXED, __HIP_MEMORY_SCOPE_AGENT);
          int sb = __hip_atomic_load(stamp1 + (64+tid)*32, __ATOMIC_RELAXED, __HIP_MEMORY_SCOPE_AGENT);
          int s = sa < sb ? sa : sb;
          #pragma unroll
          for (int off = 32; off; off >>= 1){
            int s2 = __shfl_xor(s, off);
            s = s < s2 ? s : s2;
          }
          credit = s;
          if (credit < t - 7) __builtin_amdgcn_s_sleep(8);
        }
      }
      __syncthreads();
      // ---- h-part: 32 forced-in-flight loads, one drain, then 64 MFMA ----
      {
        h8 st[32];
        #pragma unroll
        for (int i = 0; i < 8; ++i){
          int hcol = wave*256 + i*32 + quad*8;
          #pragma unroll
          for (int mt = 0; mt < 4; ++mt)
            cld16(st[i*4 + mt], hA + ((size_t)(mt*16 + id) << 10) + hcol);
        }
        vm_drain();
        #pragma unroll
        for (int i = 0; i < 8; ++i)
          #pragma unroll
          for (int mt = 0; mt < 4; ++mt){
            a0[mt] = __builtin_amdgcn_mfma_f32_16x16x32_f16(st[i*4+mt], w0[2+i], a0[mt], 0,0,0);
            a1[mt] = __builtin_amdgcn_mfma_f32_16x16x32_f16(st[i*4+mt], w1[2+i], a1[mt], 0,0,0);
          }
      }
      // ---- exchange: D lane(id,quad) reg r -> batch mt*16+quad*4+r, row f*16+id ----
      #pragma unroll
      for (int mt = 0; mt < 4; ++mt){
        *(f32x4*)&Gs[wave][id][mt*16 + quad*4]      = a0[mt];
        *(f32x4*)&Gs[wave][16 + id][mt*16 + quad*4] = a1[mt];
      }
      __syncthreads();
      // ---- cell phase: 2 cells (batch cb, j = j0 + jq*2 + jj) ----
      ushort2 hb; float2 hf;
      #pragma unroll
      for (int jj = 0; jj < 2; ++jj){
        int jl = jq*2 + jj;
        float p[4];
        #pragma unroll
        for (int g = 0; g < 4; ++g){
          int e = (g >> 1)*16 + (g & 1)*8 + jl;
          p[g] = Gs[0][e][cb] + Gs[1][e][cb] + Gs[2][e][cb] + Gs[3][e][cb] + bs[g][jj];
        }
        float iv = sigm(p[0]), fv = sigm(p[1]), gv = tanh_f(p[2]), ov = sigm(p[3]);
        float c = fv*c2[jj] + iv*gv;
        c2[jj] = c;
        float h = ov * tanh_f(c);
        (&hf.x)[jj] = h;
        ((u16*)&hb)[jj] = f2h(h);
      }
      union { ushort2 s; unsigned int v; } pk; pk.s = hb;
      __hip_atomic_store((unsigned int*)&hout[(size_t)cb*HH + j0 + jq*2],
                         pk.v, __ATOMIC_RELAXED, __HIP_MEMORY_SCOPE_AGENT);
      if (t == TT - 1)
        *(float2*)&hfin[(size_t)cb*HH + j0 + jq*2] = hf;
      __syncthreads();   // drains vmcnt: h-stores ack'd at coherence point
      if (tid == 0)
        __hip_atomic_store(stamp0 + jg*32, t + 1, __ATOMIC_RELAXED, __HIP_MEMORY_SCOPE_AGENT);
    }
  } else {
    // ---- preload weight fragment: 16 steps x 2 frags = 128 VGPR ----
    h8 w0[16], w1[16];
    const int wb = wave * 16;
    #pragma unroll
    for (int l = 0; l < 16; ++l){
      const u16* wl = Wblk + (size_t)(wb + l)*1024 + lane*8;
      w0[l] = *(const h8*)(wl);
      w1[l] = *(const h8*)(wl + 512);
    }
    // wave w covers k [w*512, (w+1)*512): waves 0-1 read y0, waves 2-3 read h1
    const int koff = (wave & 1) * 512;
    for (int t = 0; t < TT; ++t){
      const u16* y0  = h0buf + ((size_t)((t + 1) & 7) << 16); // y0[t] = h0[t]
      const u16* hA1 = h1buf + ((size_t)(t & 7) << 16);       // h1[t-1]
      u16* hout      = h1buf + ((size_t)((t + 1) & 7) << 16); // h1[t]
      const u16* hsrc = (wave < 2) ? y0 : hA1;
      // ---- wait: L0 published h0[t] (stamp >= t+1); L1 peers published h1[t-1] ----
      if (tid < 128){
        while (__hip_atomic_load(stamp0 + tid*32, __ATOMIC_RELAXED, __HIP_MEMORY_SCOPE_AGENT) < t + 1)
          __builtin_amdgcn_s_sleep(2);
      } else {
        while (__hip_atomic_load(stamp1 + (tid & 127)*32, __ATOMIC_RELAXED, __HIP_MEMORY_SCOPE_AGENT) < t)
          __builtin_amdgcn_s_sleep(2);
      }
      __syncthreads();
      f32x4 a0[4] = {}, a1[4] = {};
      // ---- phase A: 32 forced-in-flight loads (ksteps 0-7), drain, 64 MFMA ----
      {
        h8 st[32];
        #pragma unroll
        for (int l = 0; l < 8; ++l){
          int col = koff + l*32 + quad*8;
          #pragma unroll
          for (int mt = 0; mt < 4; ++mt)
            cld16(st[l*4 + mt], hsrc + ((size_t)(mt*16 + id) << 10) + col);
        }
        vm_drain();
        #pragma unroll
        for (int l = 0; l < 8; ++l)
          #pragma unroll
          for (int mt = 0; mt < 4; ++mt){
            a0[mt] = __builtin_amdgcn_mfma_f32_16x16x32_f16(st[l*4+mt], w0[l], a0[mt], 0,0,0);
            a1[mt] = __builtin_amdgcn_mfma_f32_16x16x32_f16(st[l*4+mt], w1[l], a1[mt], 0,0,0);
          }
      }
      // ---- phase B: 32 forced-in-flight loads (ksteps 8-15), drain, 64 MFMA ----
      {
        h8 st[32];
        #pragma unroll
        for (int l = 0; l < 8; ++l){
          int col = koff + (8 + l)*32 + quad*8;
          #pragma unroll
          for (int mt = 0; mt < 4; ++mt)
            cld16(st[l*4 + mt], hsrc + ((size_t)(mt*16 + id) << 10) + col);
        }
        vm_drain();
        #pragma unroll
        for (int l = 0; l < 8; ++l)
          #pragma unroll
          for (int mt = 0; mt < 4; ++mt){
            a0[mt] = __builtin_amdgcn_mfma_f32_16x16x32_f16(st[l*4+mt], w0[8+l], a0[mt], 0,0,0);
            a1[mt] = __builtin_amdgcn_mfma_f32_16x16x32_f16(st[l*4+mt], w1[8+l], a1[mt], 0,0,0);
          }
      }
      #pragma unroll
      for (int mt = 0; mt < 4; ++mt){
        *(f32x4*)&Gs[wave][id][mt*16 + quad*4]      = a0[mt];
        *(f32x4*)&Gs[wave][16 + id][mt*16 + quad*4] = a1[mt];
      }
      __syncthreads();
      ushort2 hb; float2 hf;
      #pragma unroll
      for (int jj = 0; jj < 2; ++jj){
        int jl = jq*2 + jj;
        float p[4];
        #pragma unroll
        for (int g = 0; g < 4; ++g){
          int e = (g >> 1)*16 + (g & 1)*8 + jl;
          p[g] = Gs[0][e][cb] + Gs[1][e][cb] + Gs[2][e][cb] + Gs[3][e][cb] + bs[g][jj];
        }
        float iv = sigm(p[0]), fv = sigm(p[1]), gv = tanh_f(p[2]), ov = sigm(p[3]);
        float c = fv*c2[jj] + iv*gv;
        c2[jj] = c;
        float h = ov * tanh_f(c);
        (&hf.x)[jj] = h;
        ((u16*)&hb)[jj] = f2h(h);
      }
      union { ushort2 s; unsigned int v; } pk; pk.s = hb;
      __hip_atomic_store((unsigned int*)&hout[(size_t)cb*HH + j0 + jq*2],
                         pk.v, __ATOMIC_RELAXED, __HIP_MEMORY_SCOPE_AGENT);
      if (t == TT - 1)
        *(float2*)&hfin[(size_t)(BB*HH) + (size_t)cb*HH + j0 + jq*2] = hf;
      __syncthreads();   // drains vmcnt: h-stores ack'd at coherence point
      if (tid == 0)
        __hip_atomic_store(stamp1 + jg*32, t + 1, __ATOMIC_RELAXED, __HIP_MEMORY_SCOPE_AGENT);
    }
  }
}

// ---------------- FC head ----------------
__global__ void fc_kernel(const float* __restrict__ hfin, const float* __restrict__ fcw,
                          const float* __restrict__ fcb, float* __restrict__ out){
  int row = blockIdx.x;          // 0..127  (0..63 layer0 hT, 64..127 layer1 hT)
  int lane = threadIdx.x;        // 64
  const float* h = hfin + (size_t)row*HH;
  float a0 = 0.f, a1 = 0.f;
  for (int j = lane; j < HH; j += 64){
    float v = h[j]; v = v > 0.f ? v : 0.f;
    a0 += v * fcw[j];
    a1 += v * fcw[HH + j];
  }
  for (int off = 32; off; off >>= 1){ a0 += __shfl_down(a0, off); a1 += __shfl_down(a1, off); }
  if (lane == 0){
    out[row*2 + 0] = 1.f/(1.f + __expf(-(a0 + fcb[0])));
    out[row*2 + 1] = 1.f/(1.f + __expf(-(a1 + fcb[1])));
  }
}

// ---------------- launch ----------------
extern "C" void kernel_launch(void* const* d_in, const int* in_sizes, int n_in,
                              void* d_out, int out_size, void* d_ws, size_t ws_size,
                              hipStream_t stream){
  (void)in_sizes; (void)n_in; (void)out_size; (void)ws_size;
  const float* x    = (const float*)d_in[0];
  const float* Wih0 = (const float*)d_in[1];
  const float* Whh0 = (const float*)d_in[2];
  const float* bih0 = (const float*)d_in[3];
  const float* bhh0 = (const float*)d_in[4];
  const float* Wih1 = (const float*)d_in[5];
  const float* Whh1 = (const float*)d_in[6];
  const float* bih1 = (const float*)d_in[7];
  const float* bhh1 = (const float*)d_in[8];
  const float* fcw  = (const float*)d_in[9];
  const float* fcb  = (const float*)d_in[10];

  char* w = (char*)d_ws;
  size_t off = 0;
  auto take = [&](size_t bytes)->char*{
    char* p = w + off; off += (bytes + 255) & ~(size_t)255; return p;
  };
  u16*   xb    = (u16*)  take((size_t)TT*BB*II*2);       // 16 MB
  u16*   wsw0  = (u16*)  take((size_t)G4*1280*2);        // 10 MB  (K=256+1024)
  u16*   wsw1  = (u16*)  take((size_t)G4*2048*2);        // 16 MB  (K=1024+1024)
  float* bias0 = (float*)take(G4*4);
  float* bias1 = (float*)take(G4*4);
  u16*   h0buf = (u16*)  take(8*(size_t)BB*HH*2);        // 1 MB ring (8 slots)
  u16*   h1buf = (u16*)  take(8*(size_t)BB*HH*2);
  float* hfin  = (float*)take(2*(size_t)BB*HH*4);        // 512 KB
  int*   stamp0= (int*)  take(128*128);                  // 128 slots x 128B
  int*   stamp1= (int*)  take(128*128);

  hipMemsetAsync(h0buf, 0, 8*(size_t)BB*HH*2, stream);
  hipMemsetAsync(h1buf, 0, 8*(size_t)BB*HH*2, stream);
  hipMemsetAsync(stamp0, 0, 128*128, stream);
  hipMemsetAsync(stamp1, 0, 128*128, stream);

  bias_comb_kernel<<<16, 256, 0, stream>>>(bih0, bhh0, bias0, G4);
  bias_comb_kernel<<<16, 256, 0, stream>>>(bih1, bhh1, bias1, G4);
  xconv_kernel<<<TT*BB, 64, 0, stream>>>(x, xb);
  // L0: 128*40*2*64/256 = 2560 blocks; L1: 128*64*2*64/256 = 4096 blocks
  wswz_kernel<<<2560, 256, 0, stream>>>(Wih0, II, Whh0, HH, wsw0, 40);
  wswz_kernel<<<4096, 256, 0, stream>>>(Wih1, HH, Whh1, HH, wsw1, 64);

  lstm_fused_kernel<<<256, 256, 0, stream>>>(xb, wsw0, wsw1, bias0, bias1,
                                             h0buf, h1buf, hfin, stamp0, stamp1);
  fc_kernel<<<2*BB, 64, 0, stream>>>(hfin, fcw, fcb, (float*)d_out);
}

// Round 12
// 5056.373 us; speedup vs baseline: 2.1576x; 1.0096x over previous
//
#include <hip/hip_runtime.h>
#include <hip/hip_bf16.h>
#include <hip/hip_fp16.h>
#include <stdint.h>

#define BB 64
#define TT 512
#define II 256
#define HH 1024
#define G4 4096

typedef unsigned short u16;
typedef unsigned long long u64;
typedef __attribute__((ext_vector_type(8))) _Float16 h8;
typedef __attribute__((ext_vector_type(4))) float f32x4;

__device__ __forceinline__ u16 f2h(float x){
  _Float16 h = (_Float16)x;
  return __builtin_bit_cast(u16, h);
}
__device__ __forceinline__ float sigm(float x){ return 1.0f/(1.0f + __expf(-x)); }
__device__ __forceinline__ float tanh_f(float x){ return 1.0f - 2.0f/(1.0f + __expf(2.0f*x)); }

// coherent read-through 16B load, ISSUE ONLY (no wait): inline asm so the
// compiler can neither sink it nor shrink the in-flight window. sc0 sc1 =
// gfx950 coherent read (reads through to the coherence point). Freshness is
// guaranteed by the stamp handshake (producer drains store-acks before
// stamping), so plain read-through loads suffice.
__device__ __forceinline__ void cld16(h8& dst, const u16* p){
  asm volatile("global_load_dwordx4 %0, %1, off sc0 sc1" : "=v"(dst) : "v"(p));
}
// drain + scheduler fence (hipcc hoists register-only MFMA past inline-asm
// s_waitcnt; sched_barrier(0) is the documented fix).
__device__ __forceinline__ void vm_drain(){
  asm volatile("s_waitcnt vmcnt(0)" ::: "memory");
  __builtin_amdgcn_sched_barrier(0);
}

// ---------------- prep kernels ----------------
__global__ void bias_comb_kernel(const float* __restrict__ a, const float* __restrict__ b,
                                 float* __restrict__ o, int n){
  int i = blockIdx.x*blockDim.x + threadIdx.x;
  if (i < n) o[i] = a[i] + b[i];
}

// x: [B][T][I] fp32 -> xb: [(t*B+b)][I] fp16
__global__ void xconv_kernel(const float* __restrict__ x, u16* __restrict__ xb){
  int m = blockIdx.x;            // t*BB + b
  int t = m >> 6, b = m & 63;
  const float4* src = (const float4*)(x + ((size_t)b*TT + t)*II);
  float4 v = src[threadIdx.x];   // 64 threads * 4 = 256 = II
  ushort4 o; o.x=f2h(v.x); o.y=f2h(v.y); o.z=f2h(v.z); o.w=f2h(v.w);
  ((ushort4*)(xb + (size_t)m*II))[threadIdx.x] = o;
}

// Concat-K weight swizzle into MFMA B-frag order (fp32 -> fp16).
// 8-j blocks: frag f in {0,1}; within frag, id in [0,16):
//   gate g = f*2 + (id>>3), j = jg8*8 + (id&7), n = g*HH + j
//   k = ks*32 + quad*8 + elem
// dst s8 = ((jg8*KS + ks)*2 + f)*64 + lane, 8 u16 each.
__global__ void wswz_kernel(const float* __restrict__ Wa, int Ka,
                            const float* __restrict__ Wb, int Kb,
                            u16* __restrict__ dst, int KS){
  int s8 = blockIdx.x*blockDim.x + threadIdx.x;
  int lane = s8 & 63;
  int f    = (s8 >> 6) & 1;
  int rest = s8 >> 7;
  int ks   = rest % KS;
  int jg8  = rest / KS;
  if (jg8 >= 128) return;
  int id = lane & 15, quad = lane >> 4;
  int g = f*2 + (id >> 3);
  int n = g*HH + jg8*8 + (id & 7);
  int k = ks*32 + quad*8;
  const float* src = (k < Ka) ? (Wa + (size_t)n*Ka + k) : (Wb + (size_t)n*Kb + (k - Ka));
  float4 v0 = ((const float4*)src)[0];
  float4 v1 = ((const float4*)src)[1];
  ushort4 o0; o0.x=f2h(v0.x); o0.y=f2h(v0.y); o0.z=f2h(v0.z); o0.w=f2h(v0.w);
  ushort4 o1; o1.x=f2h(v1.x); o1.y=f2h(v1.y); o1.z=f2h(v1.z); o1.w=f2h(v1.w);
  u16* d = dst + (size_t)s8*8;
  ((ushort4*)d)[0] = o0;
  ((ushort4*)d)[1] = o1;
}

// ---------------- fused 2-layer persistent LSTM ----------------
// ROUND-10 BASE (5.10 ms, verified) + ONE isolated change:
//  * WAVE-LOCAL waits, no pre-GEMM barrier. Each wave spins on its own
//    producer subset (one stamp per lane). L1 waves 0-1 (y0: L0 runs ahead,
//    wait nearly always pre-satisfied) start their loads+MFMAs immediately,
//    overlapping waves 2-3's binding stamp1 wait. L0 waves wait only on the
//    32 producers covering their K-slice. Gs safety: the exchange barrier
//    (writes->reads) and end barrier (reads->next-epoch writes + store-ack
//    drain) are unchanged; wave0's credit check precedes the exchange
//    barrier, so it transitively guards all stores.
// L1 load staging stays the PROVEN two-phase st[32] structure (round-11's
// 64-deep cluster is suspected in the crash and is NOT retried here).
__launch_bounds__(256, 1)
__global__ void lstm_fused_kernel(const u16* __restrict__ xb,
                                  const u16* __restrict__ Wsw0,
                                  const u16* __restrict__ Wsw1,
                                  const float* __restrict__ bias0,
                                  const float* __restrict__ bias1,
                                  u16* __restrict__ h0buf,   // 8 slots [64][1024] fp16
                                  u16* __restrict__ h1buf,   // 8 slots
                                  float* __restrict__ hfin,  // [2][64][1024] fp32
                                  int* __restrict__ stamp0,  // 128 slots, stride 32 ints
                                  int* __restrict__ stamp1){ // 128 slots, stride 32 ints
  __shared__ float Gs[4][32][68];    // [wave][gate-row 2f x 16id][batch 64+pad]
  const int blk = blockIdx.x;
  const int layer = blk >> 7;
  const int jg = blk & 127;
  const int tid = threadIdx.x, wave = tid >> 6, lane = tid & 63;
  const int id = lane & 15, quad = lane >> 4;
  const int KS = layer ? 64 : 40;
  const u16* Wblk = (layer ? Wsw1 : Wsw0) + (size_t)jg * KS * 1024;
  const int cb = tid >> 2, jq = tid & 3;  // cell phase: batch cb, j-pair jq
  const int j0 = jg * 8;
  const float* Bp = layer ? bias1 : bias0;
  float bs[4][2];
  #pragma unroll
  for (int g = 0; g < 4; ++g)
    #pragma unroll
    for (int jj = 0; jj < 2; ++jj)
      bs[g][jj] = Bp[g*HH + j0 + jq*2 + jj];
  float c2[2] = {0.f, 0.f};

  if (layer == 0){
    // ---- weights: wave w owns x-ksteps {2w,2w+1} + h-ksteps {8+8w..8+8w+7} ----
    h8 w0[10], w1[10];
    #pragma unroll
    for (int i = 0; i < 10; ++i){
      int ks = (i < 2) ? (2*wave + i) : (8 + 8*wave + (i - 2));
      const u16* wl = Wblk + (size_t)ks*1024 + lane*8;
      w0[i] = *(const h8*)(wl);
      w1[i] = *(const h8*)(wl + 512);
    }
    // wave w's h cols [w*256, w*256+256) come from producers jg in [w*32, w*32+32)
    const int* myst = stamp0 + (wave*32 + (lane & 31))*32;
    int credit = 0;
    for (int t = 0; t < TT; ++t){
      const u16* hA = h0buf + ((size_t)(t & 7) << 16);        // h0[t-1]
      u16* hout     = h0buf + ((size_t)((t + 1) & 7) << 16);  // h0[t]
      f32x4 a0[4] = {}, a1[4] = {};
      // ---- x-part: h-independent, runs before/under the stamp wait ----
      #pragma unroll
      for (int i = 0; i < 2; ++i){
        int xcol = (2*wave + i)*32 + quad*8;
        #pragma unroll
        for (int mt = 0; mt < 4; ++mt){
          h8 A = *(const h8*)(xb + (((size_t)t*64 + mt*16 + id) << 8) + xcol);
          a0[mt] = __builtin_amdgcn_mfma_f32_16x16x32_f16(A, w0[i], a0[mt], 0,0,0);
          a1[mt] = __builtin_amdgcn_mfma_f32_16x16x32_f16(A, w1[i], a1[mt], 0,0,0);
        }
      }
      // ---- wave-local wait: my 32 producers published h0[t-1] ----
      while (__hip_atomic_load(myst, __ATOMIC_RELAXED, __HIP_MEMORY_SCOPE_AGENT) < t)
        __builtin_amdgcn_s_sleep(2);
      // ---- lazy anti-overwrite credit (wave0): slot (t+1)&7 = y0[t-8] needs L1 >= t-7.
      //      Stores happen after the exchange barrier, so wave0's check guards all waves.
      if (wave == 0){
        while (credit < t - 7){
          int sa = __hip_atomic_load(stamp1 + lane*32,      __ATOMIC_RELAXED, __HIP_MEMORY_SCOPE_AGENT);
          int sb = __hip_atomic_load(stamp1 + (64+lane)*32, __ATOMIC_RELAXED, __HIP_MEMORY_SCOPE_AGENT);
          int s = sa < sb ? sa : sb;
          #pragma unroll
          for (int off = 32; off; off >>= 1){
            int s2 = __shfl_xor(s, off);
            s = s < s2 ? s : s2;
          }
          credit = s;
          if (credit < t - 7) __builtin_amdgcn_s_sleep(8);
        }
      }
      // ---- h-part: 32 forced-in-flight loads, one drain, then 64 MFMA ----
      {
        h8 st[32];
        #pragma unroll
        for (int i = 0; i < 8; ++i){
          int hcol = wave*256 + i*32 + quad*8;
          #pragma unroll
          for (int mt = 0; mt < 4; ++mt)
            cld16(st[i*4 + mt], hA + ((size_t)(mt*16 + id) << 10) + hcol);
        }
        vm_drain();
        #pragma unroll
        for (int i = 0; i < 8; ++i)
          #pragma unroll
          for (int mt = 0; mt < 4; ++mt){
            a0[mt] = __builtin_amdgcn_mfma_f32_16x16x32_f16(st[i*4+mt], w0[2+i], a0[mt], 0,0,0);
            a1[mt] = __builtin_amdgcn_mfma_f32_16x16x32_f16(st[i*4+mt], w1[2+i], a1[mt], 0,0,0);
          }
      }
      // ---- exchange: D lane(id,quad) reg r -> batch mt*16+quad*4+r, row f*16+id ----
      #pragma unroll
      for (int mt = 0; mt < 4; ++mt){
        *(f32x4*)&Gs[wave][id][mt*16 + quad*4]      = a0[mt];
        *(f32x4*)&Gs[wave][16 + id][mt*16 + quad*4] = a1[mt];
      }
      __syncthreads();   // exchange barrier (also gates stores on wave0's credit)
      // ---- cell phase: 2 cells (batch cb, j = j0 + jq*2 + jj) ----
      ushort2 hb; float2 hf;
      #pragma unroll
      for (int jj = 0; jj < 2; ++jj){
        int jl = jq*2 + jj;
        float p[4];
        #pragma unroll
        for (int g = 0; g < 4; ++g){
          int e = (g >> 1)*16 + (g & 1)*8 + jl;
          p[g] = Gs[0][e][cb] + Gs[1][e][cb] + Gs[2][e][cb] + Gs[3][e][cb] + bs[g][jj];
        }
        float iv = sigm(p[0]), fv = sigm(p[1]), gv = tanh_f(p[2]), ov = sigm(p[3]);
        float c = fv*c2[jj] + iv*gv;
        c2[jj] = c;
        float h = ov * tanh_f(c);
        (&hf.x)[jj] = h;
        ((u16*)&hb)[jj] = f2h(h);
      }
      union { ushort2 s; unsigned int v; } pk; pk.s = hb;
      __hip_atomic_store((unsigned int*)&hout[(size_t)cb*HH + j0 + jq*2],
                         pk.v, __ATOMIC_RELAXED, __HIP_MEMORY_SCOPE_AGENT);
      if (t == TT - 1)
        *(float2*)&hfin[(size_t)cb*HH + j0 + jq*2] = hf;
      __syncthreads();   // end barrier: drains store acks; protects Gs reuse
      if (tid == 0)
        __hip_atomic_store(stamp0 + jg*32, t + 1, __ATOMIC_RELAXED, __HIP_MEMORY_SCOPE_AGENT);
    }
  } else {
    // ---- preload weight fragment: 16 steps x 2 frags = 128 regs ----
    h8 w0[16], w1[16];
    const int wb = wave * 16;
    #pragma unroll
    for (int l = 0; l < 16; ++l){
      const u16* wl = Wblk + (size_t)(wb + l)*1024 + lane*8;
      w0[l] = *(const h8*)(wl);
      w1[l] = *(const h8*)(wl + 512);
    }
    // waves 0-1: y0 halves (producers = stamp0 slots (wave&1)*64+lane, need >= t+1);
    // waves 2-3: h1 halves (producers = stamp1 slots (wave&1)*64+lane, need >= t)
    const int koff = (wave & 1) * 512;
    const int* myst = ((wave < 2) ? stamp0 : stamp1) + ((wave & 1)*64 + lane)*32;
    for (int t = 0; t < TT; ++t){
      const u16* y0  = h0buf + ((size_t)((t + 1) & 7) << 16); // y0[t] = h0[t]
      const u16* hA1 = h1buf + ((size_t)(t & 7) << 16);       // h1[t-1]
      u16* hout      = h1buf + ((size_t)((t + 1) & 7) << 16); // h1[t]
      const u16* hsrc = (wave < 2) ? y0 : hA1;
      const int need  = (wave < 2) ? (t + 1) : t;
      // ---- wave-local wait (divergent spin; reconvergence = wave-wide AND) ----
      while (__hip_atomic_load(myst, __ATOMIC_RELAXED, __HIP_MEMORY_SCOPE_AGENT) < need)
        __builtin_amdgcn_s_sleep(2);
      f32x4 a0[4] = {}, a1[4] = {};
      // ---- phase A: 32 forced-in-flight loads (ksteps 0-7), drain, 64 MFMA ----
      {
        h8 st[32];
        #pragma unroll
        for (int l = 0; l < 8; ++l){
          int col = koff + l*32 + quad*8;
          #pragma unroll
          for (int mt = 0; mt < 4; ++mt)
            cld16(st[l*4 + mt], hsrc + ((size_t)(mt*16 + id) << 10) + col);
        }
        vm_drain();
        #pragma unroll
        for (int l = 0; l < 8; ++l)
          #pragma unroll
          for (int mt = 0; mt < 4; ++mt){
            a0[mt] = __builtin_amdgcn_mfma_f32_16x16x32_f16(st[l*4+mt], w0[l], a0[mt], 0,0,0);
            a1[mt] = __builtin_amdgcn_mfma_f32_16x16x32_f16(st[l*4+mt], w1[l], a1[mt], 0,0,0);
          }
      }
      // ---- phase B: 32 forced-in-flight loads (ksteps 8-15), drain, 64 MFMA ----
      {
        h8 st[32];
        #pragma unroll
        for (int l = 0; l < 8; ++l){
          int col = koff + (8 + l)*32 + quad*8;
          #pragma unroll
          for (int mt = 0; mt < 4; ++mt)
            cld16(st[l*4 + mt], hsrc + ((size_t)(mt*16 + id) << 10) + col);
        }
        vm_drain();
        #pragma unroll
        for (int l = 0; l < 8; ++l)
          #pragma unroll
          for (int mt = 0; mt < 4; ++mt){
            a0[mt] = __builtin_amdgcn_mfma_f32_16x16x32_f16(st[l*4+mt], w0[8+l], a0[mt], 0,0,0);
            a1[mt] = __builtin_amdgcn_mfma_f32_16x16x32_f16(st[l*4+mt], w1[8+l], a1[mt], 0,0,0);
          }
      }
      #pragma unroll
      for (int mt = 0; mt < 4; ++mt){
        *(f32x4*)&Gs[wave][id][mt*16 + quad*4]      = a0[mt];
        *(f32x4*)&Gs[wave][16 + id][mt*16 + quad*4] = a1[mt];
      }
      __syncthreads();   // exchange barrier
      ushort2 hb; float2 hf;
      #pragma unroll
      for (int jj = 0; jj < 2; ++jj){
        int jl = jq*2 + jj;
        float p[4];
        #pragma unroll
        for (int g = 0; g < 4; ++g){
          int e = (g >> 1)*16 + (g & 1)*8 + jl;
          p[g] = Gs[0][e][cb] + Gs[1][e][cb] + Gs[2][e][cb] + Gs[3][e][cb] + bs[g][jj];
        }
        float iv = sigm(p[0]), fv = sigm(p[1]), gv = tanh_f(p[2]), ov = sigm(p[3]);
        float c = fv*c2[jj] + iv*gv;
        c2[jj] = c;
        float h = ov * tanh_f(c);
        (&hf.x)[jj] = h;
        ((u16*)&hb)[jj] = f2h(h);
      }
      union { ushort2 s; unsigned int v; } pk; pk.s = hb;
      __hip_atomic_store((unsigned int*)&hout[(size_t)cb*HH + j0 + jq*2],
                         pk.v, __ATOMIC_RELAXED, __HIP_MEMORY_SCOPE_AGENT);
      if (t == TT - 1)
        *(float2*)&hfin[(size_t)(BB*HH) + (size_t)cb*HH + j0 + jq*2] = hf;
      __syncthreads();   // end barrier: drains store acks (attests y0/h1 reads done)
      if (tid == 0)
        __hip_atomic_store(stamp1 + jg*32, t + 1, __ATOMIC_RELAXED, __HIP_MEMORY_SCOPE_AGENT);
    }
  }
}

// ---------------- FC head ----------------
__global__ void fc_kernel(const float* __restrict__ hfin, const float* __restrict__ fcw,
                          const float* __restrict__ fcb, float* __restrict__ out){
  int row = blockIdx.x;          // 0..127  (0..63 layer0 hT, 64..127 layer1 hT)
  int lane = threadIdx.x;        // 64
  const float* h = hfin + (size_t)row*HH;
  float a0 = 0.f, a1 = 0.f;
  for (int j = lane; j < HH; j += 64){
    float v = h[j]; v = v > 0.f ? v : 0.f;
    a0 += v * fcw[j];
    a1 += v * fcw[HH + j];
  }
  for (int off = 32; off; off >>= 1){ a0 += __shfl_down(a0, off); a1 += __shfl_down(a1, off); }
  if (lane == 0){
    out[row*2 + 0] = 1.f/(1.f + __expf(-(a0 + fcb[0])));
    out[row*2 + 1] = 1.f/(1.f + __expf(-(a1 + fcb[1])));
  }
}

// ---------------- launch ----------------
extern "C" void kernel_launch(void* const* d_in, const int* in_sizes, int n_in,
                              void* d_out, int out_size, void* d_ws, size_t ws_size,
                              hipStream_t stream){
  (void)in_sizes; (void)n_in; (void)out_size; (void)ws_size;
  const float* x    = (const float*)d_in[0];
  const float* Wih0 = (const float*)d_in[1];
  const float* Whh0 = (const float*)d_in[2];
  const float* bih0 = (const float*)d_in[3];
  const float* bhh0 = (const float*)d_in[4];
  const float* Wih1 = (const float*)d_in[5];
  const float* Whh1 = (const float*)d_in[6];
  const float* bih1 = (const float*)d_in[7];
  const float* bhh1 = (const float*)d_in[8];
  const float* fcw  = (const float*)d_in[9];
  const float* fcb  = (const float*)d_in[10];

  char* w = (char*)d_ws;
  size_t off = 0;
  auto take = [&](size_t bytes)->char*{
    char* p = w + off; off += (bytes + 255) & ~(size_t)255; return p;
  };
  u16*   xb    = (u16*)  take((size_t)TT*BB*II*2);       // 16 MB
  u16*   wsw0  = (u16*)  take((size_t)G4*1280*2);        // 10 MB  (K=256+1024)
  u16*   wsw1  = (u16*)  take((size_t)G4*2048*2);        // 16 MB  (K=1024+1024)
  float* bias0 = (float*)take(G4*4);
  float* bias1 = (float*)take(G4*4);
  u16*   h0buf = (u16*)  take(8*(size_t)BB*HH*2);        // 1 MB ring (8 slots)
  u16*   h1buf = (u16*)  take(8*(size_t)BB*HH*2);
  float* hfin  = (float*)take(2*(size_t)BB*HH*4);        // 512 KB
  int*   stamp0= (int*)  take(128*128);                  // 128 slots x 128B
  int*   stamp1= (int*)  take(128*128);

  hipMemsetAsync(h0buf, 0, 8*(size_t)BB*HH*2, stream);
  hipMemsetAsync(h1buf, 0, 8*(size_t)BB*HH*2, stream);
  hipMemsetAsync(stamp0, 0, 128*128, stream);
  hipMemsetAsync(stamp1, 0, 128*128, stream);

  bias_comb_kernel<<<16, 256, 0, stream>>>(bih0, bhh0, bias0, G4);
  bias_comb_kernel<<<16, 256, 0, stream>>>(bih1, bhh1, bias1, G4);
  xconv_kernel<<<TT*BB, 64, 0, stream>>>(x, xb);
  // L0: 128*40*2*64/256 = 2560 blocks; L1: 128*64*2*64/256 = 4096 blocks
  wswz_kernel<<<2560, 256, 0, stream>>>(Wih0, II, Whh0, HH, wsw0, 40);
  wswz_kernel<<<4096, 256, 0, stream>>>(Wih1, HH, Whh1, HH, wsw1, 64);

  lstm_fused_kernel<<<256, 256, 0, stream>>>(xb, wsw0, wsw1, bias0, bias1,
                                             h0buf, h1buf, hfin, stamp0, stamp1);
  fc_kernel<<<2*BB, 64, 0, stream>>>(hfin, fcw, fcb, (float*)d_out);
}